// Round 2
// baseline (179.687 us; speedup 1.0000x reference)
//
#include <hip/hip_runtime.h>
#include <hip/hip_bf16.h>

// DLRM forward, MI355X. Split-f16 MFMA GEMMs (hi/lo weight split + on-the-fly
// activation split => ~fp32 accuracy), f16 MFMA interaction, fused prep.
//
// Dims: B=8192, bottom 13->512->256->64, 26 tables x 100000 x 64,
// interaction 27x27 strict lower tri = 351, top 415->512->256->1.

typedef _Float16 f16x8 __attribute__((ext_vector_type(8)));
typedef float f32x4 __attribute__((ext_vector_type(4)));

struct F16Pair { _Float16 hi, lo; };
__device__ __forceinline__ F16Pair split_f32(float v) {
  F16Pair p;
  p.hi = (_Float16)v;
  p.lo = (_Float16)(v - (float)p.hi);
  return p;
}

// ---------------------------------------------------------------------------
// Fused prep: pad+copy dense_x to [8192][32] f32; split 5 weight matrices into
// (hi,lo) f16 pairs with K padded to {32,512,256,416,512}.
// Segment element counts: 262144, 16384, 131072, 16384, 212992, 131072
// total = 770048 = 3008 blocks * 256.
// ---------------------------------------------------------------------------
__global__ __launch_bounds__(256) void prep_kernel(
    const float* __restrict__ dense,
    const float* __restrict__ bW0, const float* __restrict__ bW1,
    const float* __restrict__ bW2, const float* __restrict__ tW0,
    const float* __restrict__ tW1,
    float* __restrict__ xd,
    _Float16* __restrict__ w0h, _Float16* __restrict__ w0l,
    _Float16* __restrict__ w1h, _Float16* __restrict__ w1l,
    _Float16* __restrict__ w2h, _Float16* __restrict__ w2l,
    _Float16* __restrict__ t0h, _Float16* __restrict__ t0l,
    _Float16* __restrict__ t1h, _Float16* __restrict__ t1l)
{
  int i = blockIdx.x * 256 + threadIdx.x;
  if (i < 262144) {  // dense pad [8192][13] -> [8192][32] f32
    int m = i >> 5, k = i & 31;
    xd[i] = (k < 13) ? dense[m * 13 + k] : 0.0f;
    return;
  }
  i -= 262144;
  if (i < 16384) {   // bW0 [512][13] -> [512][32] split
    int m = i >> 5, k = i & 31;
    float v = (k < 13) ? bW0[m * 13 + k] : 0.0f;
    F16Pair p = split_f32(v); w0h[i] = p.hi; w0l[i] = p.lo;
    return;
  }
  i -= 16384;
  if (i < 131072) {  // bW1 [256][512]
    F16Pair p = split_f32(bW1[i]); w1h[i] = p.hi; w1l[i] = p.lo; return;
  }
  i -= 131072;
  if (i < 16384) {   // bW2 [64][256]
    F16Pair p = split_f32(bW2[i]); w2h[i] = p.hi; w2l[i] = p.lo; return;
  }
  i -= 16384;
  if (i < 212992) {  // tW0 [512][415] -> [512][416] split
    int m = i / 416, k = i - m * 416;
    float v = (k < 415) ? tW0[m * 415 + k] : 0.0f;
    F16Pair p = split_f32(v); t0h[i] = p.hi; t0l[i] = p.lo;
    return;
  }
  i -= 212992;
  if (i < 131072) {  // tW1 [256][512]
    F16Pair p = split_f32(tW1[i]); t1h[i] = p.hi; t1l[i] = p.lo; return;
  }
}

// ---------------------------------------------------------------------------
// Split-f16 MFMA GEMM:  C[b][m] = relu( sum_k A[b][k] * W[m][k] + bias[m] )
// A fp32 [B][K] (K multiple of 32), W pre-split (hi,lo) f16 [M][K].
// Block = 256 thr = 4 waves; wave computes 16 rows x 64 cols.
// Per k-step: A loaded fp32 -> split in regs; 3 MFMAs per 16-col tile.
// Fragment k-mapping cancels between A and B (same assumed mapping), so only
// the HW-verified C/D layout (col=lane&15, row=(lane>>4)*4+reg) matters.
// ---------------------------------------------------------------------------
template <int K, int M, bool RELU>
__global__ __launch_bounds__(256) void gemm_split_kernel(
    const float* __restrict__ A, const _Float16* __restrict__ Wh,
    const _Float16* __restrict__ Wl, const float* __restrict__ bias,
    float* __restrict__ C)
{
  const int lane = threadIdx.x & 63;
  const int wv = threadIdx.x >> 6;
  const int b0 = blockIdx.x * 64 + wv * 16;
  const int c0 = blockIdx.y * 64;
  const int rc = lane & 15;           // A-row within tile == B-col within tile
  const int ko = (lane >> 4) * 8;     // k offset of this lane's 8 elements
  const float* Ap = A + (size_t)(b0 + rc) * K + ko;
  const _Float16* Whp = Wh + (size_t)(c0 + rc) * K + ko;
  const _Float16* Wlp = Wl + (size_t)(c0 + rc) * K + ko;
  f32x4 acc[4] = {};
  for (int k = 0; k < K; k += 32) {
    float4 a0 = *(const float4*)(Ap + k);
    float4 a1 = *(const float4*)(Ap + k + 4);
    float av[8] = {a0.x, a0.y, a0.z, a0.w, a1.x, a1.y, a1.z, a1.w};
    f16x8 ah, al;
#pragma unroll
    for (int e = 0; e < 8; ++e) {
      F16Pair p = split_f32(av[e]);
      ah[e] = p.hi;
      al[e] = p.lo;
    }
#pragma unroll
    for (int j = 0; j < 4; ++j) {
      f16x8 wh = *(const f16x8*)(Whp + (size_t)(j * 16) * K + k);
      f16x8 wl = *(const f16x8*)(Wlp + (size_t)(j * 16) * K + k);
      acc[j] = __builtin_amdgcn_mfma_f32_16x16x32_f16(ah, wh, acc[j], 0, 0, 0);
      acc[j] = __builtin_amdgcn_mfma_f32_16x16x32_f16(ah, wl, acc[j], 0, 0, 0);
      acc[j] = __builtin_amdgcn_mfma_f32_16x16x32_f16(al, wh, acc[j], 0, 0, 0);
    }
  }
  const int rr0 = (lane >> 4) * 4;
#pragma unroll
  for (int j = 0; j < 4; ++j) {
    float bs = bias[c0 + j * 16 + rc];
#pragma unroll
    for (int r = 0; r < 4; ++r) {
      float v = acc[j][r] + bs;
      if (RELU) v = fmaxf(v, 0.0f);
      C[(size_t)(b0 + rr0 + r) * M + c0 + j * 16 + rc] = v;
    }
  }
}

// ---------------------------------------------------------------------------
// Gather + interaction. One wave per batch row.
// T = [x3(1x64); emb(26x64)] padded to 32 rows. Z = T*T^T via 6 f16 MFMAs
// (tiles (0,0),(1,0),(1,1) x 2 k-halves; B-frag of T^T == A-frag of T).
// Writes R[b] = [x3 (64 f32), Zflat (351 f32), 0 pad] stride 416.
// ---------------------------------------------------------------------------
__global__ __launch_bounds__(256) void interact_kernel(
    const float* __restrict__ x3, const float* __restrict__ Wemb,
    const int* __restrict__ lSi, float* __restrict__ R)
{
  const int lane = threadIdx.x & 63;
  const int wv = threadIdx.x >> 6;
  const int b = blockIdx.x * 4 + wv;
  const int r16 = lane & 15;
  const int ko = (lane >> 4) * 8;

  f16x8 frag[2][2];
#pragma unroll
  for (int rt = 0; rt < 2; ++rt) {
    const int gr = rt * 16 + r16;  // global T row this lane supplies
    const float* src = nullptr;
    if (gr == 0) {
      src = x3 + (size_t)b * 64;
    } else if (gr <= 26) {
      int idx = lSi[(size_t)(gr - 1) * 8192 + b];
      src = Wemb + ((size_t)(gr - 1) * 100000 + (size_t)idx) * 64;
    }
#pragma unroll
    for (int kh = 0; kh < 2; ++kh) {
      f16x8 f = {};
      if (src) {
        const float* s = src + kh * 32 + ko;
        float4 lo4 = *(const float4*)s;
        float4 hi4 = *(const float4*)(s + 4);
        f[0] = (_Float16)lo4.x; f[1] = (_Float16)lo4.y;
        f[2] = (_Float16)lo4.z; f[3] = (_Float16)lo4.w;
        f[4] = (_Float16)hi4.x; f[5] = (_Float16)hi4.y;
        f[6] = (_Float16)hi4.z; f[7] = (_Float16)hi4.w;
      }
      frag[rt][kh] = f;
    }
  }

  f32x4 z00 = {}, z10 = {}, z11 = {};
#pragma unroll
  for (int kh = 0; kh < 2; ++kh) {
    z00 = __builtin_amdgcn_mfma_f32_16x16x32_f16(frag[0][kh], frag[0][kh], z00, 0, 0, 0);
    z10 = __builtin_amdgcn_mfma_f32_16x16x32_f16(frag[1][kh], frag[0][kh], z10, 0, 0, 0);
    z11 = __builtin_amdgcn_mfma_f32_16x16x32_f16(frag[1][kh], frag[1][kh], z11, 0, 0, 0);
  }

  float* Rb = R + (size_t)b * 416;
  Rb[lane] = x3[(size_t)b * 64 + lane];   // x part (exact fp32 copy)
  if (lane == 0) Rb[415] = 0.0f;          // K-pad for top-MLP GEMM

  const int col = lane & 15;
  const int rr0 = (lane >> 4) * 4;
#pragma unroll
  for (int r = 0; r < 4; ++r) {
    const int i0 = rr0 + r;               // tile (0,0): rows 0..15, cols 0..15
    if (i0 > col) Rb[64 + i0 * (i0 - 1) / 2 + col] = z00[r];
    const int i1 = 16 + rr0 + r;          // tiles (1,0)/(1,1): rows 16..26
    if (i1 < 27) {
      Rb[64 + i1 * (i1 - 1) / 2 + col] = z10[r];
      const int j1 = 16 + col;
      if (i1 > j1) Rb[64 + i1 * (i1 - 1) / 2 + j1] = z11[r];
    }
  }
}

// ---------------------------------------------------------------------------
// Final layer: p[b] = sigmoid( dot(z2[b][0:256], tW2) + tb2 ), one wave/row.
// ---------------------------------------------------------------------------
__global__ __launch_bounds__(256) void top2_kernel(
    const float* __restrict__ z2, const float* __restrict__ W,
    const float* __restrict__ b2, float* __restrict__ out)
{
  const int lane = threadIdx.x & 63;
  const int wv = threadIdx.x >> 6;
  const int row = blockIdx.x * 4 + wv;
  float4 zv = *(const float4*)(z2 + (size_t)row * 256 + lane * 4);
  float4 wv4 = *(const float4*)(W + lane * 4);
  float s = zv.x * wv4.x + zv.y * wv4.y + zv.z * wv4.z + zv.w * wv4.w;
#pragma unroll
  for (int off = 32; off > 0; off >>= 1) s += __shfl_xor(s, off, 64);
  if (lane == 0) out[row] = 1.0f / (1.0f + expf(-(s + b2[0])));
}

// ---------------------------------------------------------------------------
extern "C" void kernel_launch(void* const* d_in, const int* in_sizes, int n_in,
                              void* d_out, int out_size, void* d_ws, size_t ws_size,
                              hipStream_t stream)
{
  (void)in_sizes; (void)n_in; (void)out_size; (void)ws_size;
  const float* dense = (const float*)d_in[0];
  const int*   lSi   = (const int*)d_in[1];     // lS_o (d_in[2]) unused
  const float* Wemb  = (const float*)d_in[3];
  const float* bW0 = (const float*)d_in[4];  const float* bb0 = (const float*)d_in[5];
  const float* bW1 = (const float*)d_in[6];  const float* bb1 = (const float*)d_in[7];
  const float* bW2 = (const float*)d_in[8];  const float* bb2 = (const float*)d_in[9];
  const float* tW0 = (const float*)d_in[10]; const float* tb0 = (const float*)d_in[11];
  const float* tW1 = (const float*)d_in[12]; const float* tb1 = (const float*)d_in[13];
  const float* tW2 = (const float*)d_in[14]; const float* tb2 = (const float*)d_in[15];
  float* out = (float*)d_out;

  char* ws = (char*)d_ws;
  size_t off = 0;
  auto alloc = [&](size_t bytes) -> void* {
    void* p = ws + off;
    off += (bytes + 255) & ~(size_t)255;
    return p;
  };
  float*    xd  = (float*)alloc((size_t)262144 * 4);   // dense padded [8192][32]
  _Float16* w0h = (_Float16*)alloc((size_t)16384 * 2);
  _Float16* w0l = (_Float16*)alloc((size_t)16384 * 2);
  _Float16* w1h = (_Float16*)alloc((size_t)131072 * 2);
  _Float16* w1l = (_Float16*)alloc((size_t)131072 * 2);
  _Float16* w2h = (_Float16*)alloc((size_t)16384 * 2);
  _Float16* w2l = (_Float16*)alloc((size_t)16384 * 2);
  _Float16* t0h = (_Float16*)alloc((size_t)212992 * 2);
  _Float16* t0l = (_Float16*)alloc((size_t)212992 * 2);
  _Float16* t1h = (_Float16*)alloc((size_t)131072 * 2);
  _Float16* t1l = (_Float16*)alloc((size_t)131072 * 2);
  float* x1 = (float*)alloc((size_t)8192 * 512 * 4);
  float* x2 = (float*)alloc((size_t)8192 * 256 * 4);
  float* x3 = (float*)alloc((size_t)8192 * 64 * 4);
  float* R  = (float*)alloc((size_t)8192 * 416 * 4);
  float* z1 = x1;  // x1 dead after bottom layer 1 -> reuse for top layer 0 out
  float* z2 = x2;  // x2 dead after bottom layer 2 -> reuse for top layer 1 out

  prep_kernel<<<3008, 256, 0, stream>>>(dense, bW0, bW1, bW2, tW0, tW1, xd,
                                        w0h, w0l, w1h, w1l, w2h, w2l,
                                        t0h, t0l, t1h, t1l);
  gemm_split_kernel<32, 512, true><<<dim3(128, 8), 256, 0, stream>>>(xd, w0h, w0l, bb0, x1);
  gemm_split_kernel<512, 256, true><<<dim3(128, 4), 256, 0, stream>>>(x1, w1h, w1l, bb1, x2);
  gemm_split_kernel<256, 64, true><<<dim3(128, 1), 256, 0, stream>>>(x2, w2h, w2l, bb2, x3);
  interact_kernel<<<2048, 256, 0, stream>>>(x3, Wemb, lSi, R);
  gemm_split_kernel<416, 512, true><<<dim3(128, 8), 256, 0, stream>>>(R, t0h, t0l, tb0, z1);
  gemm_split_kernel<512, 256, true><<<dim3(128, 4), 256, 0, stream>>>(z1, t1h, t1l, tb1, z2);
  top2_kernel<<<2048, 256, 0, stream>>>(z2, tW2, tb2, out);
}

// Round 3
// 74.436 us; speedup vs baseline: 2.4140x; 2.4140x over previous
//
#include <hip/hip_runtime.h>
#include <hip/hip_bf16.h>

// DLRM forward, MI355X — round 3: pure-f16 MFMA everywhere (1 MFMA per
// product), weights LDS-staged with XOR swizzle, f16 activations.
// Dims: B=8192, bottom 13->512->256->64, 26x100000x64 emb, tri(27)=351,
// top 415->512->256->1. K padded to 64-multiples: 64,512,256,448,512.

typedef _Float16 f16x8 __attribute__((ext_vector_type(8)));
typedef _Float16 f16x4 __attribute__((ext_vector_type(4)));
typedef float f32x4 __attribute__((ext_vector_type(4)));

// ---------------------------------------------------------------------------
// prep: cast/pad everything to f16.
// segments: xd 8192x64=524288 | w0 512x64=32768 | w1 131072 | w2 16384 |
//           t0 512x448=229376 | t1 131072  => total 1064960 = 4160*256
// ---------------------------------------------------------------------------
__global__ __launch_bounds__(256) void prep_kernel(
    const float* __restrict__ dense,
    const float* __restrict__ bW0, const float* __restrict__ bW1,
    const float* __restrict__ bW2, const float* __restrict__ tW0,
    const float* __restrict__ tW1,
    _Float16* __restrict__ xd,
    _Float16* __restrict__ w0, _Float16* __restrict__ w1,
    _Float16* __restrict__ w2, _Float16* __restrict__ t0,
    _Float16* __restrict__ t1)
{
  int i = blockIdx.x * 256 + threadIdx.x;
  if (i < 524288) {  // dense pad [8192][13] -> [8192][64]
    int m = i >> 6, k = i & 63;
    xd[i] = (_Float16)((k < 13) ? dense[m * 13 + k] : 0.0f);
    return;
  }
  i -= 524288;
  if (i < 32768) {   // bW0 [512][13] -> [512][64]
    int m = i >> 6, k = i & 63;
    w0[i] = (_Float16)((k < 13) ? bW0[m * 13 + k] : 0.0f);
    return;
  }
  i -= 32768;
  if (i < 131072) { w1[i] = (_Float16)bW1[i]; return; }   // [256][512]
  i -= 131072;
  if (i < 16384) { w2[i] = (_Float16)bW2[i]; return; }    // [64][256]
  i -= 16384;
  if (i < 229376) {  // tW0 [512][415] -> [512][448]
    int m = i / 448, k = i - m * 448;
    t0[i] = (_Float16)((k < 415) ? tW0[m * 415 + k] : 0.0f);
    return;
  }
  i -= 229376;
  if (i < 131072) { t1[i] = (_Float16)tW1[i]; return; }   // [256][512]
}

// ---------------------------------------------------------------------------
// f16 GEMM: C[b][m] = relu(sum_k A[b][k]*W[m][k] + bias[m]), all f16 except
// bias/acc fp32. Block = 4 waves; wave tile = WROWS x BN. W tile (BN x 64k)
// staged to LDS with XOR swizzle (f16 idx ^= (col&7)*8) so both the staging
// ds_write_b128 and the stride-128B ds_read_b128 are bank-balanced.
// Per k-chunk(64): 2 barriers; per kk-step(32): NR A-loads (f16x8 global),
// NJ LDS W-loads, NR*NJ MFMAs. LDS feeds 2 MFMAs per 16B/lane => ~105 B/cyc
// at MFMA peak, just under the 112 B/cyc LDS ceiling.
// ---------------------------------------------------------------------------
template <int K, int M, int BN, int WROWS, bool RELU>
__global__ __launch_bounds__(256) void gemm_f16(
    const _Float16* __restrict__ A, const _Float16* __restrict__ W,
    const float* __restrict__ bias, _Float16* __restrict__ C)
{
  constexpr int BM = 4 * WROWS;
  constexpr int NR = WROWS / 16;
  constexpr int NJ = BN / 16;
  __shared__ _Float16 Wlds[BN * 64];

  const int t = threadIdx.x;
  const int lane = t & 63, wv = t >> 6;
  const int rc = lane & 15, g = lane >> 4;
  const int ko = g * 8;
  const int r0 = blockIdx.x * BM + wv * WROWS;
  const int c0 = blockIdx.y * BN;

  f32x4 acc[NR][NJ] = {};

  for (int kc = 0; kc < K; kc += 64) {
    __syncthreads();
#pragma unroll
    for (int p = 0; p < BN / 32; ++p) {
      int chunk = t + 256 * p;
      int c = chunk >> 3;            // 8 x 16B chunks per 64-k col row
      int kk8 = (chunk & 7) * 8;
      *(f16x8*)(&Wlds[c * 64 + (kk8 ^ ((c & 7) * 8))]) =
          *(const f16x8*)(&W[(size_t)(c0 + c) * K + kc + kk8]);
    }
    __syncthreads();
#pragma unroll
    for (int kk = 0; kk < 64; kk += 32) {
      f16x8 af[NR];
#pragma unroll
      for (int rt = 0; rt < NR; ++rt)
        af[rt] = *(const f16x8*)(&A[(size_t)(r0 + rt * 16 + rc) * K + kc + kk + ko]);
#pragma unroll
      for (int j = 0; j < NJ; ++j) {
        const int col = j * 16 + rc;
        f16x8 wf = *(const f16x8*)(&Wlds[col * 64 + ((kk + ko) ^ ((col & 7) * 8))]);
#pragma unroll
        for (int rt = 0; rt < NR; ++rt)
          acc[rt][j] = __builtin_amdgcn_mfma_f32_16x16x32_f16(af[rt], wf, acc[rt][j], 0, 0, 0);
      }
    }
  }

  const int rr0 = g * 4;
#pragma unroll
  for (int j = 0; j < NJ; ++j) {
    const float bs = bias[c0 + j * 16 + rc];
#pragma unroll
    for (int rt = 0; rt < NR; ++rt)
#pragma unroll
      for (int r = 0; r < 4; ++r) {
        float v = acc[rt][j][r] + bs;
        if (RELU) v = fmaxf(v, 0.0f);
        C[(size_t)(r0 + rt * 16 + rr0 + r) * M + c0 + j * 16 + rc] = (_Float16)v;
      }
  }
}

// ---------------------------------------------------------------------------
// Gather + interaction, one wave per batch row. T = [x3(1x64); emb(26x64)]
// padded to 32 rows, Z = T*T^T via 6 MFMAs. R[b] = [x3 f16 (64), Zflat (351),
// zeros to 448] stride 448 (t0 K-pad).
// ---------------------------------------------------------------------------
__global__ __launch_bounds__(256) void interact_kernel(
    const _Float16* __restrict__ x3, const float* __restrict__ Wemb,
    const int* __restrict__ lSi, _Float16* __restrict__ R)
{
  const int lane = threadIdx.x & 63;
  const int wv = threadIdx.x >> 6;
  const int b = blockIdx.x * 4 + wv;
  const int r16 = lane & 15;
  const int ko = (lane >> 4) * 8;

  f16x8 frag[2][2];
#pragma unroll
  for (int rt = 0; rt < 2; ++rt) {
    const int gr = rt * 16 + r16;
    if (gr == 0) {
#pragma unroll
      for (int kh = 0; kh < 2; ++kh)
        frag[rt][kh] = *(const f16x8*)(x3 + (size_t)b * 64 + kh * 32 + ko);
    } else if (gr <= 26) {
      int idx = lSi[(size_t)(gr - 1) * 8192 + b];
      const float* src = Wemb + ((size_t)(gr - 1) * 100000 + (size_t)idx) * 64;
#pragma unroll
      for (int kh = 0; kh < 2; ++kh) {
        const float* s = src + kh * 32 + ko;
        float4 lo4 = *(const float4*)s;
        float4 hi4 = *(const float4*)(s + 4);
        f16x8 f;
        f[0] = (_Float16)lo4.x; f[1] = (_Float16)lo4.y;
        f[2] = (_Float16)lo4.z; f[3] = (_Float16)lo4.w;
        f[4] = (_Float16)hi4.x; f[5] = (_Float16)hi4.y;
        f[6] = (_Float16)hi4.z; f[7] = (_Float16)hi4.w;
        frag[rt][kh] = f;
      }
    } else {
      f16x8 z = {};
      frag[rt][0] = z; frag[rt][1] = z;
    }
  }

  f32x4 z00 = {}, z10 = {}, z11 = {};
#pragma unroll
  for (int kh = 0; kh < 2; ++kh) {
    z00 = __builtin_amdgcn_mfma_f32_16x16x32_f16(frag[0][kh], frag[0][kh], z00, 0, 0, 0);
    z10 = __builtin_amdgcn_mfma_f32_16x16x32_f16(frag[1][kh], frag[0][kh], z10, 0, 0, 0);
    z11 = __builtin_amdgcn_mfma_f32_16x16x32_f16(frag[1][kh], frag[1][kh], z11, 0, 0, 0);
  }

  _Float16* Rb = R + (size_t)b * 448;
  Rb[lane] = x3[(size_t)b * 64 + lane];        // x part
  if (lane < 33) Rb[415 + lane] = (_Float16)0.0f;  // K-pad 415..447

  const int col = lane & 15;
  const int rr0 = (lane >> 4) * 4;
#pragma unroll
  for (int r = 0; r < 4; ++r) {
    const int i0 = rr0 + r;
    if (i0 > col) Rb[64 + i0 * (i0 - 1) / 2 + col] = (_Float16)z00[r];
    const int i1 = 16 + rr0 + r;
    if (i1 < 27) {
      Rb[64 + i1 * (i1 - 1) / 2 + col] = (_Float16)z10[r];
      const int j1 = 16 + col;
      if (i1 > j1) Rb[64 + i1 * (i1 - 1) / 2 + j1] = (_Float16)z11[r];
    }
  }
}

// ---------------------------------------------------------------------------
// Final: p[b] = sigmoid(dot(z2[b], tW2) + tb2), one wave/row.
// ---------------------------------------------------------------------------
__global__ __launch_bounds__(256) void top2_kernel(
    const _Float16* __restrict__ z2, const float* __restrict__ W,
    const float* __restrict__ b2, float* __restrict__ out)
{
  const int lane = threadIdx.x & 63;
  const int wv = threadIdx.x >> 6;
  const int row = blockIdx.x * 4 + wv;
  f16x4 zv = *(const f16x4*)(z2 + (size_t)row * 256 + lane * 4);
  float4 wv4 = *(const float4*)(W + lane * 4);
  float s = (float)zv[0] * wv4.x + (float)zv[1] * wv4.y +
            (float)zv[2] * wv4.z + (float)zv[3] * wv4.w;
#pragma unroll
  for (int off = 32; off > 0; off >>= 1) s += __shfl_xor(s, off, 64);
  if (lane == 0) out[row] = 1.0f / (1.0f + expf(-(s + b2[0])));
}

// ---------------------------------------------------------------------------
extern "C" void kernel_launch(void* const* d_in, const int* in_sizes, int n_in,
                              void* d_out, int out_size, void* d_ws, size_t ws_size,
                              hipStream_t stream)
{
  (void)in_sizes; (void)n_in; (void)out_size; (void)ws_size;
  const float* dense = (const float*)d_in[0];
  const int*   lSi   = (const int*)d_in[1];     // lS_o (d_in[2]) unused
  const float* Wemb  = (const float*)d_in[3];
  const float* bW0 = (const float*)d_in[4];  const float* bb0 = (const float*)d_in[5];
  const float* bW1 = (const float*)d_in[6];  const float* bb1 = (const float*)d_in[7];
  const float* bW2 = (const float*)d_in[8];  const float* bb2 = (const float*)d_in[9];
  const float* tW0 = (const float*)d_in[10]; const float* tb0 = (const float*)d_in[11];
  const float* tW1 = (const float*)d_in[12]; const float* tb1 = (const float*)d_in[13];
  const float* tW2 = (const float*)d_in[14]; const float* tb2 = (const float*)d_in[15];
  float* out = (float*)d_out;

  char* ws = (char*)d_ws;
  size_t off = 0;
  auto alloc = [&](size_t bytes) -> void* {
    void* p = ws + off;
    off += (bytes + 255) & ~(size_t)255;
    return p;
  };
  _Float16* xd = (_Float16*)alloc((size_t)524288 * 2);   // [8192][64]
  _Float16* w0 = (_Float16*)alloc((size_t)32768 * 2);    // [512][64]
  _Float16* w1 = (_Float16*)alloc((size_t)131072 * 2);   // [256][512]
  _Float16* w2 = (_Float16*)alloc((size_t)16384 * 2);    // [64][256]
  _Float16* t0 = (_Float16*)alloc((size_t)229376 * 2);   // [512][448]
  _Float16* t1 = (_Float16*)alloc((size_t)131072 * 2);   // [256][512]
  _Float16* x1 = (_Float16*)alloc((size_t)8192 * 512 * 2);
  _Float16* x2 = (_Float16*)alloc((size_t)8192 * 256 * 2);
  _Float16* x3 = (_Float16*)alloc((size_t)8192 * 64 * 2);
  _Float16* R  = (_Float16*)alloc((size_t)8192 * 448 * 2);
  _Float16* z1 = x1;  // dead after bottom L1
  _Float16* z2 = x2;  // dead after bottom L2

  prep_kernel<<<4160, 256, 0, stream>>>(dense, bW0, bW1, bW2, tW0, tW1,
                                        xd, w0, w1, w2, t0, t1);
  gemm_f16< 64, 512, 128, 32, true><<<dim3(64, 4), 256, 0, stream>>>(xd, w0, bb0, x1);
  gemm_f16<512, 256,  64, 32, true><<<dim3(64, 4), 256, 0, stream>>>(x1, w1, bb1, x2);
  gemm_f16<256,  64,  64, 16, true><<<dim3(128, 1), 256, 0, stream>>>(x2, w2, bb2, x3);
  interact_kernel<<<2048, 256, 0, stream>>>(x3, Wemb, lSi, R);
  gemm_f16<448, 512, 128, 32, true><<<dim3(64, 4), 256, 0, stream>>>(R, t0, tb0, z1);
  gemm_f16<512, 256,  64, 32, true><<<dim3(64, 4), 256, 0, stream>>>(z1, t1, tb1, z2);
  top2_kernel<<<2048, 256, 0, stream>>>(z2, tW2, tb2, out);
}

// Round 4
// 66.852 us; speedup vs baseline: 2.6878x; 1.1135x over previous
//
#include <hip/hip_runtime.h>
#include <hip/hip_bf16.h>

// DLRM forward, MI355X — round 4: f16 MFMA GEMMs with pre-tiled+pre-swizzled
// weights, global_load_lds staging, double-buffered 2-phase K-loop (1 barrier
// per 64-K chunk). Dims: B=8192, bottom 13->512->256->64, 26x100000x64 emb,
// tri(27)=351, top 415->512->256->1. K padded: 64,512,256,448,512. BN=64.

typedef _Float16 f16x8 __attribute__((ext_vector_type(8)));
typedef _Float16 f16x4 __attribute__((ext_vector_type(4)));
typedef float f32x4 __attribute__((ext_vector_type(4)));

__device__ __forceinline__ void load_lds_16B(const _Float16* g, _Float16* l) {
  __builtin_amdgcn_global_load_lds(
      (const __attribute__((address_space(1))) void*)g,
      (__attribute__((address_space(3))) void*)l, 16, 0, 0);
}

// ---------------------------------------------------------------------------
// prep: xd = pad(dense) f16 [8192][64]; weights -> tiled/swizzled f16.
// Tiled layout (BN=64): element (c,k) of [M][Kpad] lives at
//   ((ic*NCH + ik)*64 + cl)*64 + (kl ^ ((cl&7)*8)),  ic=c/64,cl=c%64,
//   ik=k/64,kl=k%64.  GEMM stages each 64x64 tile linearly via
//   global_load_lds; ds_read uses the same XOR -> bank-balanced.
// segments: xd 524288 | w0 32768 | w1 131072 | w2 16384 | t0 229376 |
//           t1 131072  => 1064960 = 4160*256
// ---------------------------------------------------------------------------
__device__ __forceinline__ void tile_store(
    _Float16* __restrict__ dst, const float* __restrict__ src,
    int i, int Korig, int NCH)
{
  int klx = i & 63;
  int tmp = i >> 6;
  int cl = tmp & 63;
  int tq = tmp >> 6;
  int ik = tq % NCH;
  int ic = tq / NCH;
  int kl = klx ^ ((cl & 7) * 8);
  int c = ic * 64 + cl;
  int k = ik * 64 + kl;
  dst[i] = (_Float16)((k < Korig) ? src[(size_t)c * Korig + k] : 0.0f);
}

__global__ __launch_bounds__(256) void prep_kernel(
    const float* __restrict__ dense,
    const float* __restrict__ bW0, const float* __restrict__ bW1,
    const float* __restrict__ bW2, const float* __restrict__ tW0,
    const float* __restrict__ tW1,
    _Float16* __restrict__ xd,
    _Float16* __restrict__ w0, _Float16* __restrict__ w1,
    _Float16* __restrict__ w2, _Float16* __restrict__ t0,
    _Float16* __restrict__ t1)
{
  int i = blockIdx.x * 256 + threadIdx.x;
  if (i < 524288) {  // dense pad [8192][13] -> [8192][64] (row-major, no tile)
    int m = i >> 6, k = i & 63;
    xd[i] = (_Float16)((k < 13) ? dense[m * 13 + k] : 0.0f);
    return;
  }
  i -= 524288;
  if (i < 32768)  { tile_store(w0, bW0, i, 13, 1);  return; }  // [512][64]
  i -= 32768;
  if (i < 131072) { tile_store(w1, bW1, i, 512, 8); return; }  // [256][512]
  i -= 131072;
  if (i < 16384)  { tile_store(w2, bW2, i, 256, 4); return; }  // [64][256]
  i -= 16384;
  if (i < 229376) { tile_store(t0, tW0, i, 415, 7); return; }  // [512][448]
  i -= 229376;
  if (i < 131072) { tile_store(t1, tW1, i, 512, 8); return; }  // [256][512]
}

// ---------------------------------------------------------------------------
// f16 GEMM: C[b][m] = relu(sum_k A[b][k]*W[m][k] + bias[m]).
// A row-major f16 [B][K]; Wt tiled/swizzled (see prep). Block = 4 waves,
// wave tile WROWS x 64. 2-phase K-loop: stage(chunk+1) -> compute(chunk) ->
// one __syncthreads per chunk (vmcnt drain covered by compute).
// ---------------------------------------------------------------------------
template <int K, int M, int WROWS, bool RELU>
__global__ __launch_bounds__(256) void gemm_f16(
    const _Float16* __restrict__ A, const _Float16* __restrict__ Wt,
    const float* __restrict__ bias, _Float16* __restrict__ C)
{
  constexpr int BM = 4 * WROWS;
  constexpr int NR = WROWS / 16;
  constexpr int NCH = K / 64;
  __shared__ _Float16 Wlds[2][64 * 64];

  const int t = threadIdx.x;
  const int lane = t & 63, wv = t >> 6;
  const int rc = lane & 15, g = lane >> 4;
  const int ko = g * 8;
  const int r0 = blockIdx.x * BM + wv * WROWS;
  const int c0 = blockIdx.y * 64;
  const _Float16* Wb = Wt + (size_t)blockIdx.y * NCH * 4096;

  auto stage = [&](int buf, int ch) {
    const _Float16* src = Wb + (size_t)ch * 4096 + (size_t)(wv * 64 + lane) * 8;
    _Float16* dst = &Wlds[buf][(size_t)wv * 512];
    load_lds_16B(src, dst);
    load_lds_16B(src + 2048, dst + 2048);
  };

  f32x4 acc[NR][4] = {};
  stage(0, 0);
  __syncthreads();

  for (int ch = 0; ch < NCH; ++ch) {
    const int buf = ch & 1;
    if (ch + 1 < NCH) stage(buf ^ 1, ch + 1);
#pragma unroll
    for (int kk = 0; kk < 64; kk += 32) {
      f16x8 af[NR];
#pragma unroll
      for (int rt = 0; rt < NR; ++rt)
        af[rt] = *(const f16x8*)(&A[(size_t)(r0 + rt * 16 + rc) * K + ch * 64 + kk + ko]);
#pragma unroll
      for (int j = 0; j < 4; ++j) {
        const int col = j * 16 + rc;
        f16x8 wf = *(const f16x8*)(&Wlds[buf][col * 64 + ((kk + ko) ^ ((col & 7) * 8))]);
#pragma unroll
        for (int rt = 0; rt < NR; ++rt)
          acc[rt][j] = __builtin_amdgcn_mfma_f32_16x16x32_f16(af[rt], wf, acc[rt][j], 0, 0, 0);
      }
    }
    __syncthreads();
  }

  const int rr0 = g * 4;
#pragma unroll
  for (int j = 0; j < 4; ++j) {
    const float bs = bias[c0 + j * 16 + rc];
#pragma unroll
    for (int rt = 0; rt < NR; ++rt)
#pragma unroll
      for (int r = 0; r < 4; ++r) {
        float v = acc[rt][j][r] + bs;
        if (RELU) v = fmaxf(v, 0.0f);
        C[(size_t)(r0 + rt * 16 + rr0 + r) * M + c0 + j * 16 + rc] = (_Float16)v;
      }
  }
}

// ---------------------------------------------------------------------------
// Gather + interaction, one wave per batch row. T = [x3(1x64); emb(26x64)]
// padded to 32 rows, Z = T*T^T via 6 MFMAs. R[b] = [x3 f16 (64), Zflat (351),
// zeros to 448] stride 448.
// ---------------------------------------------------------------------------
__global__ __launch_bounds__(256) void interact_kernel(
    const _Float16* __restrict__ x3, const float* __restrict__ Wemb,
    const int* __restrict__ lSi, _Float16* __restrict__ R)
{
  const int lane = threadIdx.x & 63;
  const int wv = threadIdx.x >> 6;
  const int b = blockIdx.x * 4 + wv;
  const int r16 = lane & 15;
  const int ko = (lane >> 4) * 8;

  f16x8 frag[2][2];
#pragma unroll
  for (int rt = 0; rt < 2; ++rt) {
    const int gr = rt * 16 + r16;
    if (gr == 0) {
#pragma unroll
      for (int kh = 0; kh < 2; ++kh)
        frag[rt][kh] = *(const f16x8*)(x3 + (size_t)b * 64 + kh * 32 + ko);
    } else if (gr <= 26) {
      int idx = lSi[(size_t)(gr - 1) * 8192 + b];
      const float* src = Wemb + ((size_t)(gr - 1) * 100000 + (size_t)idx) * 64;
#pragma unroll
      for (int kh = 0; kh < 2; ++kh) {
        const float* s = src + kh * 32 + ko;
        float4 lo4 = *(const float4*)s;
        float4 hi4 = *(const float4*)(s + 4);
        f16x8 f;
        f[0] = (_Float16)lo4.x; f[1] = (_Float16)lo4.y;
        f[2] = (_Float16)lo4.z; f[3] = (_Float16)lo4.w;
        f[4] = (_Float16)hi4.x; f[5] = (_Float16)hi4.y;
        f[6] = (_Float16)hi4.z; f[7] = (_Float16)hi4.w;
        frag[rt][kh] = f;
      }
    } else {
      f16x8 z = {};
      frag[rt][0] = z; frag[rt][1] = z;
    }
  }

  f32x4 z00 = {}, z10 = {}, z11 = {};
#pragma unroll
  for (int kh = 0; kh < 2; ++kh) {
    z00 = __builtin_amdgcn_mfma_f32_16x16x32_f16(frag[0][kh], frag[0][kh], z00, 0, 0, 0);
    z10 = __builtin_amdgcn_mfma_f32_16x16x32_f16(frag[1][kh], frag[0][kh], z10, 0, 0, 0);
    z11 = __builtin_amdgcn_mfma_f32_16x16x32_f16(frag[1][kh], frag[1][kh], z11, 0, 0, 0);
  }

  _Float16* Rb = R + (size_t)b * 448;
  Rb[lane] = x3[(size_t)b * 64 + lane];
  if (lane < 33) Rb[415 + lane] = (_Float16)0.0f;

  const int col = lane & 15;
  const int rr0 = (lane >> 4) * 4;
#pragma unroll
  for (int r = 0; r < 4; ++r) {
    const int i0 = rr0 + r;
    if (i0 > col) Rb[64 + i0 * (i0 - 1) / 2 + col] = (_Float16)z00[r];
    const int i1 = 16 + rr0 + r;
    if (i1 < 27) {
      Rb[64 + i1 * (i1 - 1) / 2 + col] = (_Float16)z10[r];
      const int j1 = 16 + col;
      if (i1 > j1) Rb[64 + i1 * (i1 - 1) / 2 + j1] = (_Float16)z11[r];
    }
  }
}

// ---------------------------------------------------------------------------
// Final: p[b] = sigmoid(dot(z2[b], tW2) + tb2), one wave/row.
// ---------------------------------------------------------------------------
__global__ __launch_bounds__(256) void top2_kernel(
    const _Float16* __restrict__ z2, const float* __restrict__ W,
    const float* __restrict__ b2, float* __restrict__ out)
{
  const int lane = threadIdx.x & 63;
  const int wv = threadIdx.x >> 6;
  const int row = blockIdx.x * 4 + wv;
  f16x4 zv = *(const f16x4*)(z2 + (size_t)row * 256 + lane * 4);
  float4 wv4 = *(const float4*)(W + lane * 4);
  float s = (float)zv[0] * wv4.x + (float)zv[1] * wv4.y +
            (float)zv[2] * wv4.z + (float)zv[3] * wv4.w;
#pragma unroll
  for (int off = 32; off > 0; off >>= 1) s += __shfl_xor(s, off, 64);
  if (lane == 0) out[row] = 1.0f / (1.0f + expf(-(s + b2[0])));
}

// ---------------------------------------------------------------------------
extern "C" void kernel_launch(void* const* d_in, const int* in_sizes, int n_in,
                              void* d_out, int out_size, void* d_ws, size_t ws_size,
                              hipStream_t stream)
{
  (void)in_sizes; (void)n_in; (void)out_size; (void)ws_size;
  const float* dense = (const float*)d_in[0];
  const int*   lSi   = (const int*)d_in[1];     // lS_o (d_in[2]) unused
  const float* Wemb  = (const float*)d_in[3];
  const float* bW0 = (const float*)d_in[4];  const float* bb0 = (const float*)d_in[5];
  const float* bW1 = (const float*)d_in[6];  const float* bb1 = (const float*)d_in[7];
  const float* bW2 = (const float*)d_in[8];  const float* bb2 = (const float*)d_in[9];
  const float* tW0 = (const float*)d_in[10]; const float* tb0 = (const float*)d_in[11];
  const float* tW1 = (const float*)d_in[12]; const float* tb1 = (const float*)d_in[13];
  const float* tW2 = (const float*)d_in[14]; const float* tb2 = (const float*)d_in[15];
  float* out = (float*)d_out;

  char* ws = (char*)d_ws;
  size_t off = 0;
  auto alloc = [&](size_t bytes) -> void* {
    void* p = ws + off;
    off += (bytes + 255) & ~(size_t)255;
    return p;
  };
  _Float16* xd = (_Float16*)alloc((size_t)524288 * 2);   // [8192][64]
  _Float16* w0 = (_Float16*)alloc((size_t)32768 * 2);    // tiled [512][64]
  _Float16* w1 = (_Float16*)alloc((size_t)131072 * 2);   // tiled [256][512]
  _Float16* w2 = (_Float16*)alloc((size_t)16384 * 2);    // tiled [64][256]
  _Float16* t0 = (_Float16*)alloc((size_t)229376 * 2);   // tiled [512][448]
  _Float16* t1 = (_Float16*)alloc((size_t)131072 * 2);   // tiled [256][512]
  _Float16* x1 = (_Float16*)alloc((size_t)8192 * 512 * 2);
  _Float16* x2 = (_Float16*)alloc((size_t)8192 * 256 * 2);
  _Float16* x3 = (_Float16*)alloc((size_t)8192 * 64 * 2);
  _Float16* R  = (_Float16*)alloc((size_t)8192 * 448 * 2);
  _Float16* z1 = x1;  // dead after bottom L1
  _Float16* z2 = x2;  // dead after bottom L2

  prep_kernel<<<4160, 256, 0, stream>>>(dense, bW0, bW1, bW2, tW0, tW1,
                                        xd, w0, w1, w2, t0, t1);
  gemm_f16< 64, 512, 32, true><<<dim3(64, 8), 256, 0, stream>>>(xd, w0, bb0, x1);
  gemm_f16<512, 256, 32, true><<<dim3(64, 4), 256, 0, stream>>>(x1, w1, bb1, x2);
  gemm_f16<256,  64, 16, true><<<dim3(128, 1), 256, 0, stream>>>(x2, w2, bb2, x3);
  interact_kernel<<<2048, 256, 0, stream>>>(x3, Wemb, lSi, R);
  gemm_f16<448, 512, 32, true><<<dim3(64, 8), 256, 0, stream>>>(R, t0, tb0, z1);
  gemm_f16<512, 256, 32, true><<<dim3(64, 4), 256, 0, stream>>>(z1, t1, tb1, z2);
  top2_kernel<<<2048, 256, 0, stream>>>(z2, tW2, tb2, out);
}

// Round 5
// 64.866 us; speedup vs baseline: 2.7701x; 1.0306x over previous
//
#include <hip/hip_runtime.h>
#include <hip/hip_bf16.h>
#include <type_traits>

// DLRM forward, MI355X — round 5: counted-vmcnt 2-ahead pipelined f16 GEMMs
// (3 LDS buffers, raw s_barrier, no vmcnt(0) drain), pre-tiled+swizzled
// weights staged via global_load_lds, A prefetched 2 chunks ahead into regs.
// Dims: B=8192, bottom 13->512->256->64, 26x100000x64 emb, tri(27)=351,
// top 415->512->256->1. K padded: 64,512,256,448,512. BN=64.

typedef _Float16 f16x8 __attribute__((ext_vector_type(8)));
typedef _Float16 f16x4 __attribute__((ext_vector_type(4)));
typedef float f32x4 __attribute__((ext_vector_type(4)));

__device__ __forceinline__ void load_lds_16B(const _Float16* g, _Float16* l) {
  __builtin_amdgcn_global_load_lds(
      (const __attribute__((address_space(1))) void*)g,
      (__attribute__((address_space(3))) void*)l, 16, 0, 0);
}

template <int N>
__device__ __forceinline__ void wait_vmcnt() {
  asm volatile("s_waitcnt vmcnt(%0)" ::"n"(N) : "memory");
}

template <int I, int N, typename F>
__device__ __forceinline__ void sfor(F&& f) {
  if constexpr (I < N) {
    f(std::integral_constant<int, I>{});
    sfor<I + 1, N>(static_cast<F&&>(f));
  }
}

// ---------------------------------------------------------------------------
// prep: xd = pad(dense) f16 [8192][64]; weights -> tiled/swizzled f16.
// Element (c,k) of [M][Kpad] -> ((ic*NCH+ik)*64 + cl)*64 + (kl ^ ((cl&7)*8)).
// ---------------------------------------------------------------------------
__device__ __forceinline__ void tile_store(
    _Float16* __restrict__ dst, const float* __restrict__ src,
    int i, int Korig, int NCH)
{
  int klx = i & 63;
  int tmp = i >> 6;
  int cl = tmp & 63;
  int tq = tmp >> 6;
  int ik = tq % NCH;
  int ic = tq / NCH;
  int kl = klx ^ ((cl & 7) * 8);
  int c = ic * 64 + cl;
  int k = ik * 64 + kl;
  dst[i] = (_Float16)((k < Korig) ? src[(size_t)c * Korig + k] : 0.0f);
}

__global__ __launch_bounds__(256) void prep_kernel(
    const float* __restrict__ dense,
    const float* __restrict__ bW0, const float* __restrict__ bW1,
    const float* __restrict__ bW2, const float* __restrict__ tW0,
    const float* __restrict__ tW1,
    _Float16* __restrict__ xd,
    _Float16* __restrict__ w0, _Float16* __restrict__ w1,
    _Float16* __restrict__ w2, _Float16* __restrict__ t0,
    _Float16* __restrict__ t1)
{
  int i = blockIdx.x * 256 + threadIdx.x;
  if (i < 524288) {  // dense pad [8192][13] -> [8192][64] row-major
    int m = i >> 6, k = i & 63;
    xd[i] = (_Float16)((k < 13) ? dense[m * 13 + k] : 0.0f);
    return;
  }
  i -= 524288;
  if (i < 32768)  { tile_store(w0, bW0, i, 13, 1);  return; }
  i -= 32768;
  if (i < 131072) { tile_store(w1, bW1, i, 512, 8); return; }
  i -= 131072;
  if (i < 16384)  { tile_store(w2, bW2, i, 256, 4); return; }
  i -= 16384;
  if (i < 229376) { tile_store(t0, tW0, i, 415, 7); return; }
  i -= 229376;
  if (i < 131072) { tile_store(t1, tW1, i, 512, 8); return; }
}

// ---------------------------------------------------------------------------
// f16 GEMM, counted-vmcnt 2-ahead pipeline.
// Per wave per chunk: 2 global_load_lds (stage) + 2*NR A-loads => PER loads.
// iter ch: wait vmcnt(PER) [retires chunk ch's loads, keeps ch+1 in flight];
//          s_barrier; issue stage(ch+2)+loadA(ch+2); compute(ch).
// Overwrite safety: stage(ch+2) hits buf[(ch-1)%3], whose readers all passed
// this barrier (compute(ch-1) is pre-barrier in program order).
// ---------------------------------------------------------------------------
template <int K, int M, int WROWS, bool RELU>
__global__ __launch_bounds__(256) void gemm_f16(
    const _Float16* __restrict__ A, const _Float16* __restrict__ Wt,
    const float* __restrict__ bias, _Float16* __restrict__ C)
{
  constexpr int BM = 4 * WROWS;
  constexpr int NR = WROWS / 16;
  constexpr int NCH = K / 64;
  constexpr int PER = 2 + 2 * NR;
  __shared__ _Float16 Wlds[3][64 * 64];

  const int t = threadIdx.x;
  const int lane = t & 63, wv = t >> 6;
  const int rc = lane & 15, g = lane >> 4;
  const int ko = g * 8;
  const int r0 = blockIdx.x * BM + wv * WROWS;
  const int c0 = blockIdx.y * 64;
  const _Float16* Wb = Wt + (size_t)blockIdx.y * NCH * 4096;

  f16x8 areg[3][NR * 2];

  auto stage = [&](int slot, int ch) {
    const _Float16* src = Wb + (size_t)ch * 4096 + (size_t)(wv * 64 + lane) * 8;
    _Float16* dst = &Wlds[slot][(size_t)wv * 512];
    load_lds_16B(src, dst);
    load_lds_16B(src + 2048, dst + 2048);
  };
  auto loadA = [&](auto SLOT, auto CH) {
    constexpr int slot = SLOT.value;
    const int ch = CH.value;
#pragma unroll
    for (int rt = 0; rt < NR; ++rt)
#pragma unroll
      for (int kki = 0; kki < 2; ++kki)
        areg[slot][rt * 2 + kki] =
            *(const f16x8*)(&A[(size_t)(r0 + rt * 16 + rc) * K + ch * 64 + kki * 32 + ko]);
  };

  f32x4 acc[NR][4] = {};

  stage(0, 0);
  loadA(std::integral_constant<int, 0>{}, std::integral_constant<int, 0>{});
  if constexpr (NCH > 1) {
    stage(1, 1);
    loadA(std::integral_constant<int, 1>{}, std::integral_constant<int, 1>{});
  }

  sfor<0, NCH>([&](auto CH) {
    constexpr int ch = CH.value;
    constexpr int slot = ch % 3;
    wait_vmcnt<(ch + 1 < NCH) ? PER : 0>();
    __builtin_amdgcn_s_barrier();
    if constexpr (ch + 2 < NCH) {
      stage((ch + 2) % 3, ch + 2);
      loadA(std::integral_constant<int, (ch + 2) % 3>{},
            std::integral_constant<int, ch + 2>{});
    }
#pragma unroll
    for (int kki = 0; kki < 2; ++kki) {
#pragma unroll
      for (int j = 0; j < 4; ++j) {
        const int col = j * 16 + rc;
        f16x8 wf = *(const f16x8*)(&Wlds[slot][col * 64 + ((kki * 32 + ko) ^ ((col & 7) * 8))]);
#pragma unroll
        for (int rt = 0; rt < NR; ++rt)
          acc[rt][j] = __builtin_amdgcn_mfma_f32_16x16x32_f16(
              areg[slot][rt * 2 + kki], wf, acc[rt][j], 0, 0, 0);
      }
    }
  });

  const int rr0 = g * 4;
#pragma unroll
  for (int j = 0; j < 4; ++j) {
    const float bs = bias[c0 + j * 16 + rc];
#pragma unroll
    for (int rt = 0; rt < NR; ++rt)
#pragma unroll
      for (int r = 0; r < 4; ++r) {
        float v = acc[rt][j][r] + bs;
        if (RELU) v = fmaxf(v, 0.0f);
        C[(size_t)(r0 + rt * 16 + rr0 + r) * M + c0 + j * 16 + rc] = (_Float16)v;
      }
  }
}

// ---------------------------------------------------------------------------
// Gather + interaction, one wave per batch row (unchanged from r4, passed).
// ---------------------------------------------------------------------------
__global__ __launch_bounds__(256) void interact_kernel(
    const _Float16* __restrict__ x3, const float* __restrict__ Wemb,
    const int* __restrict__ lSi, _Float16* __restrict__ R)
{
  const int lane = threadIdx.x & 63;
  const int wv = threadIdx.x >> 6;
  const int b = blockIdx.x * 4 + wv;
  const int r16 = lane & 15;
  const int ko = (lane >> 4) * 8;

  f16x8 frag[2][2];
#pragma unroll
  for (int rt = 0; rt < 2; ++rt) {
    const int gr = rt * 16 + r16;
    if (gr == 0) {
#pragma unroll
      for (int kh = 0; kh < 2; ++kh)
        frag[rt][kh] = *(const f16x8*)(x3 + (size_t)b * 64 + kh * 32 + ko);
    } else if (gr <= 26) {
      int idx = lSi[(size_t)(gr - 1) * 8192 + b];
      const float* src = Wemb + ((size_t)(gr - 1) * 100000 + (size_t)idx) * 64;
#pragma unroll
      for (int kh = 0; kh < 2; ++kh) {
        const float* s = src + kh * 32 + ko;
        float4 lo4 = *(const float4*)s;
        float4 hi4 = *(const float4*)(s + 4);
        f16x8 f;
        f[0] = (_Float16)lo4.x; f[1] = (_Float16)lo4.y;
        f[2] = (_Float16)lo4.z; f[3] = (_Float16)lo4.w;
        f[4] = (_Float16)hi4.x; f[5] = (_Float16)hi4.y;
        f[6] = (_Float16)hi4.z; f[7] = (_Float16)hi4.w;
        frag[rt][kh] = f;
      }
    } else {
      f16x8 z = {};
      frag[rt][0] = z; frag[rt][1] = z;
    }
  }

  f32x4 z00 = {}, z10 = {}, z11 = {};
#pragma unroll
  for (int kh = 0; kh < 2; ++kh) {
    z00 = __builtin_amdgcn_mfma_f32_16x16x32_f16(frag[0][kh], frag[0][kh], z00, 0, 0, 0);
    z10 = __builtin_amdgcn_mfma_f32_16x16x32_f16(frag[1][kh], frag[0][kh], z10, 0, 0, 0);
    z11 = __builtin_amdgcn_mfma_f32_16x16x32_f16(frag[1][kh], frag[1][kh], z11, 0, 0, 0);
  }

  _Float16* Rb = R + (size_t)b * 448;
  Rb[lane] = x3[(size_t)b * 64 + lane];
  if (lane < 33) Rb[415 + lane] = (_Float16)0.0f;

  const int col = lane & 15;
  const int rr0 = (lane >> 4) * 4;
#pragma unroll
  for (int r = 0; r < 4; ++r) {
    const int i0 = rr0 + r;
    if (i0 > col) Rb[64 + i0 * (i0 - 1) / 2 + col] = (_Float16)z00[r];
    const int i1 = 16 + rr0 + r;
    if (i1 < 27) {
      Rb[64 + i1 * (i1 - 1) / 2 + col] = (_Float16)z10[r];
      const int j1 = 16 + col;
      if (i1 > j1) Rb[64 + i1 * (i1 - 1) / 2 + j1] = (_Float16)z11[r];
    }
  }
}

// ---------------------------------------------------------------------------
// Final: p[b] = sigmoid(dot(z2[b], tW2) + tb2), one wave/row.
// ---------------------------------------------------------------------------
__global__ __launch_bounds__(256) void top2_kernel(
    const _Float16* __restrict__ z2, const float* __restrict__ W,
    const float* __restrict__ b2, float* __restrict__ out)
{
  const int lane = threadIdx.x & 63;
  const int wv = threadIdx.x >> 6;
  const int row = blockIdx.x * 4 + wv;
  f16x4 zv = *(const f16x4*)(z2 + (size_t)row * 256 + lane * 4);
  float4 wv4 = *(const float4*)(W + lane * 4);
  float s = (float)zv[0] * wv4.x + (float)zv[1] * wv4.y +
            (float)zv[2] * wv4.z + (float)zv[3] * wv4.w;
#pragma unroll
  for (int off = 32; off > 0; off >>= 1) s += __shfl_xor(s, off, 64);
  if (lane == 0) out[row] = 1.0f / (1.0f + expf(-(s + b2[0])));
}

// ---------------------------------------------------------------------------
extern "C" void kernel_launch(void* const* d_in, const int* in_sizes, int n_in,
                              void* d_out, int out_size, void* d_ws, size_t ws_size,
                              hipStream_t stream)
{
  (void)in_sizes; (void)n_in; (void)out_size; (void)ws_size;
  const float* dense = (const float*)d_in[0];
  const int*   lSi   = (const int*)d_in[1];     // lS_o (d_in[2]) unused
  const float* Wemb  = (const float*)d_in[3];
  const float* bW0 = (const float*)d_in[4];  const float* bb0 = (const float*)d_in[5];
  const float* bW1 = (const float*)d_in[6];  const float* bb1 = (const float*)d_in[7];
  const float* bW2 = (const float*)d_in[8];  const float* bb2 = (const float*)d_in[9];
  const float* tW0 = (const float*)d_in[10]; const float* tb0 = (const float*)d_in[11];
  const float* tW1 = (const float*)d_in[12]; const float* tb1 = (const float*)d_in[13];
  const float* tW2 = (const float*)d_in[14]; const float* tb2 = (const float*)d_in[15];
  float* out = (float*)d_out;

  char* ws = (char*)d_ws;
  size_t off = 0;
  auto alloc = [&](size_t bytes) -> void* {
    void* p = ws + off;
    off += (bytes + 255) & ~(size_t)255;
    return p;
  };
  _Float16* xd = (_Float16*)alloc((size_t)524288 * 2);   // [8192][64]
  _Float16* w0 = (_Float16*)alloc((size_t)32768 * 2);    // tiled [512][64]
  _Float16* w1 = (_Float16*)alloc((size_t)131072 * 2);   // tiled [256][512]
  _Float16* w2 = (_Float16*)alloc((size_t)16384 * 2);    // tiled [64][256]
  _Float16* t0 = (_Float16*)alloc((size_t)229376 * 2);   // tiled [512][448]
  _Float16* t1 = (_Float16*)alloc((size_t)131072 * 2);   // tiled [256][512]
  _Float16* x1 = (_Float16*)alloc((size_t)8192 * 512 * 2);
  _Float16* x2 = (_Float16*)alloc((size_t)8192 * 256 * 2);
  _Float16* x3 = (_Float16*)alloc((size_t)8192 * 64 * 2);
  _Float16* R  = (_Float16*)alloc((size_t)8192 * 448 * 2);
  _Float16* z1 = x1;  // dead after bottom L1
  _Float16* z2 = x2;  // dead after bottom L2

  prep_kernel<<<4160, 256, 0, stream>>>(dense, bW0, bW1, bW2, tW0, tW1,
                                        xd, w0, w1, w2, t0, t1);
  gemm_f16< 64, 512, 32, true><<<dim3(64, 8), 256, 0, stream>>>(xd, w0, bb0, x1);
  gemm_f16<512, 256, 16, true><<<dim3(128, 4), 256, 0, stream>>>(x1, w1, bb1, x2);
  gemm_f16<256,  64, 16, true><<<dim3(128, 1), 256, 0, stream>>>(x2, w2, bb2, x3);
  interact_kernel<<<2048, 256, 0, stream>>>(x3, Wemb, lSi, R);
  gemm_f16<448, 512, 32, true><<<dim3(64, 8), 256, 0, stream>>>(R, t0, tb0, z1);
  gemm_f16<512, 256, 16, true><<<dim3(128, 4), 256, 0, stream>>>(z1, t1, tb1, z2);
  top2_kernel<<<2048, 256, 0, stream>>>(z2, tW2, tb2, out);
}

// Round 6
// 53.958 us; speedup vs baseline: 3.3301x; 1.2022x over previous
//
#include <hip/hip_runtime.h>
#include <hip/hip_bf16.h>

// DLRM forward, MI355X — round 6: TWO kernels.
//  prep: cast/pad weights to f16 row-major.
//  fused: per-block (32 batch rows, 512 thr = 8 waves) full forward pass:
//    L0 13->512, L1 512->256, L2 256->64, interact (gather+T*T^T), t0 448->512,
//    t1 512->256, dot+sigmoid. Activations in LDS (region-aliased, XOR-swizzled
//    k ^ ((row&7)<<3)); weights global->reg f16x8 fragments (L2-resident,
//    ~1 MB per block). No activation HBM traffic, no inter-kernel launches.

typedef _Float16 f16x8 __attribute__((ext_vector_type(8)));
typedef float f32x4 __attribute__((ext_vector_type(4)));

// ---------------------------------------------------------------------------
// prep: f16 weight images, K padded. segments (elements):
//  w0 [512][32]  = 16384   (bW0 [512][13], pad k>=13)
//  w1 [256][512] = 131072
//  w2 [64][256]  = 16384
//  t0 [512][448] = 229376  (tW0 [512][415], pad k>=415)
//  t1 [256][512] = 131072
// total 524288 = 2048 blocks * 256
// ---------------------------------------------------------------------------
__global__ __launch_bounds__(256) void prep_kernel(
    const float* __restrict__ bW0, const float* __restrict__ bW1,
    const float* __restrict__ bW2, const float* __restrict__ tW0,
    const float* __restrict__ tW1,
    _Float16* __restrict__ w0, _Float16* __restrict__ w1,
    _Float16* __restrict__ w2, _Float16* __restrict__ t0,
    _Float16* __restrict__ t1)
{
  int i = blockIdx.x * 256 + threadIdx.x;
  if (i < 16384) {
    int m = i >> 5, k = i & 31;
    w0[i] = (_Float16)((k < 13) ? bW0[m * 13 + k] : 0.0f);
    return;
  }
  i -= 16384;
  if (i < 131072) { w1[i] = (_Float16)bW1[i]; return; }
  i -= 131072;
  if (i < 16384) { w2[i] = (_Float16)bW2[i]; return; }
  i -= 16384;
  if (i < 229376) {
    int m = i / 448, k = i - m * 448;
    t0[i] = (_Float16)((k < 415) ? tW0[m * 415 + k] : 0.0f);
    return;
  }
  i -= 229376;
  if (i < 131072) { t1[i] = (_Float16)tW1[i]; return; }
}

// ---------------------------------------------------------------------------
// fused kernel. Block = 32 batch rows, 512 threads (8 waves).
// Wave tiles: each wave computes 32 rows x (M/8) cols per layer.
// LDS regions (total 61440 B):
//  regA 32KB: x1[32][512]f16 -> x3[32][64]f16 -> z1[32][512]f16
//  regB 28KB: dense[32][16]f32 -> x2[32][256]f16 -> R[32][448]f16 -> psum[8][32]f32
// A-frag reads/writes use swizzle  k' = k ^ ((row&7)<<3)  (16B-slot rotate).
// ---------------------------------------------------------------------------
__global__ __launch_bounds__(512, 2) void fused_kernel(
    const float* __restrict__ dense, const int* __restrict__ lSi,
    const float* __restrict__ Wemb,
    const _Float16* __restrict__ w0, const float* __restrict__ bb0,
    const _Float16* __restrict__ w1, const float* __restrict__ bb1,
    const _Float16* __restrict__ w2, const float* __restrict__ bb2,
    const _Float16* __restrict__ t0w, const float* __restrict__ tb0,
    const _Float16* __restrict__ t1w, const float* __restrict__ tb1,
    const float* __restrict__ tW2, const float* __restrict__ tb2,
    float* __restrict__ out)
{
  __shared__ __align__(16) char regA[32768];
  __shared__ __align__(16) char regB[28672];
  _Float16* x1s = (_Float16*)regA;   // [32][512]
  _Float16* x3s = (_Float16*)regA;   // [32][64]   (x1 dead)
  _Float16* z1s = (_Float16*)regA;   // [32][512]  (x3 dead)
  float*    dns = (float*)regB;      // [32][16]
  _Float16* x2s = (_Float16*)regB;   // [32][256]  (dense dead)
  _Float16* Rs  = (_Float16*)regB;   // [32][448]  (x2 dead)
  float*    psm = (float*)regB;      // [8][32]    (R dead)

  const int t = threadIdx.x;
  const int lane = t & 63, wv = t >> 6;
  const int rc = lane & 15, g = lane >> 4;
  const int ko = g * 8;
  const int sw = (rc & 7) << 3;      // A-frag k-swizzle (row&7 == rc&7)
  const int b0 = blockIdx.x * 32;

  // ---- phase 0: stage dense rows [32][13] -> LDS f32, pad k 13..15 ----
  if (t < 416) {
    int r = t / 13, c = t - r * 13;
    dns[r * 16 + c] = dense[(size_t)b0 * 13 + t];
  } else if (t < 512) {
    int q = t - 416;            // 96 = 32 rows * 3 pad cols
    int r = q / 3, c = 13 + (q - r * 3);
    dns[r * 16 + c] = 0.0f;
  }
  __syncthreads();

  // ---- phase 1: L0  x1 = relu(dense @ W0^T + bb0), K=32, 64 cols/wave ----
  {
    const int cb = wv * 64;
    f16x8 af[2];
#pragma unroll
    for (int rt = 0; rt < 2; ++rt) {
      f16x8 a = {};
      if (g < 2) {
        const float* s = &dns[(rt * 16 + rc) * 16 + ko];
        float4 u = *(const float4*)s;
        float4 v = *(const float4*)(s + 4);
        a[0] = (_Float16)u.x; a[1] = (_Float16)u.y;
        a[2] = (_Float16)u.z; a[3] = (_Float16)u.w;
        a[4] = (_Float16)v.x; a[5] = (_Float16)v.y;
        a[6] = (_Float16)v.z; a[7] = (_Float16)v.w;
      }
      af[rt] = a;
    }
    f32x4 acc[2][4] = {};
#pragma unroll
    for (int j = 0; j < 4; ++j) {
      f16x8 wf = *(const f16x8*)&w0[(size_t)(cb + j * 16 + rc) * 32 + ko];
#pragma unroll
      for (int rt = 0; rt < 2; ++rt)
        acc[rt][j] = __builtin_amdgcn_mfma_f32_16x16x32_f16(af[rt], wf, acc[rt][j], 0, 0, 0);
    }
    __syncthreads();  // dense slab dead before x1 (regA) writes? (x1 != regB; sync for x2 aliasing later is separate — this sync unneeded for regA but harmless ordering)
#pragma unroll
    for (int j = 0; j < 4; ++j) {
      const int col = cb + j * 16 + rc;
      const float bs = bb0[col];
#pragma unroll
      for (int rt = 0; rt < 2; ++rt)
#pragma unroll
        for (int r = 0; r < 4; ++r) {
          int row = rt * 16 + g * 4 + r;
          float v = fmaxf(acc[rt][j][r] + bs, 0.0f);
          x1s[row * 512 + (col ^ ((row & 7) << 3))] = (_Float16)v;
        }
    }
  }
  __syncthreads();

  // ---- phase 2: L1  x2 = relu(x1 @ W1^T + bb1), K=512, 32 cols/wave ----
  {
    const int cb = wv * 32;
    f32x4 acc[2][2] = {};
#pragma unroll
    for (int kk = 0; kk < 16; ++kk) {
      f16x8 af[2];
#pragma unroll
      for (int rt = 0; rt < 2; ++rt)
        af[rt] = *(const f16x8*)&x1s[(rt * 16 + rc) * 512 + ((kk * 32 + ko) ^ sw)];
#pragma unroll
      for (int j = 0; j < 2; ++j) {
        f16x8 wf = *(const f16x8*)&w1[(size_t)(cb + j * 16 + rc) * 512 + kk * 32 + ko];
#pragma unroll
        for (int rt = 0; rt < 2; ++rt)
          acc[rt][j] = __builtin_amdgcn_mfma_f32_16x16x32_f16(af[rt], wf, acc[rt][j], 0, 0, 0);
      }
    }
    __syncthreads();  // all x1 reads done before x2 (regB, dense dead) writes
#pragma unroll
    for (int j = 0; j < 2; ++j) {
      const int col = cb + j * 16 + rc;
      const float bs = bb1[col];
#pragma unroll
      for (int rt = 0; rt < 2; ++rt)
#pragma unroll
        for (int r = 0; r < 4; ++r) {
          int row = rt * 16 + g * 4 + r;
          float v = fmaxf(acc[rt][j][r] + bs, 0.0f);
          x2s[row * 256 + (col ^ ((row & 7) << 3))] = (_Float16)v;
        }
    }
  }
  __syncthreads();

  // ---- phase 3: L2  x3 = relu(x2 @ W2^T + bb2), K=256, waves 0-3 x 16 cols ----
  if (wv < 4) {
    const int cb = wv * 16;
    f32x4 acc[2] = {};
#pragma unroll
    for (int kk = 0; kk < 8; ++kk) {
      f16x8 af[2];
#pragma unroll
      for (int rt = 0; rt < 2; ++rt)
        af[rt] = *(const f16x8*)&x2s[(rt * 16 + rc) * 256 + ((kk * 32 + ko) ^ sw)];
      f16x8 wf = *(const f16x8*)&w2[(size_t)(cb + rc) * 256 + kk * 32 + ko];
#pragma unroll
      for (int rt = 0; rt < 2; ++rt)
        acc[rt] = __builtin_amdgcn_mfma_f32_16x16x32_f16(af[rt], wf, acc[rt], 0, 0, 0);
    }
    const int col = cb + rc;
    const float bs = bb2[col];
#pragma unroll
    for (int rt = 0; rt < 2; ++rt)
#pragma unroll
      for (int r = 0; r < 4; ++r) {
        int row = rt * 16 + g * 4 + r;
        float v = fmaxf(acc[rt][r] + bs, 0.0f);
        x3s[row * 64 + col] = (_Float16)v;   // x1 dead; plain layout
      }
  }
  __syncthreads();

  // ---- phase 4: interact — 4 rows/wave: gather emb, Z=T*T^T, fill R slab ----
  {
    int e_idx[4][2];
#pragma unroll
    for (int i = 0; i < 4; ++i) {
      const int b = b0 + wv * 4 + i;
#pragma unroll
      for (int rt = 0; rt < 2; ++rt) {
        const int gr = rt * 16 + rc;
        e_idx[i][rt] = (gr >= 1 && gr <= 26) ? lSi[(size_t)(gr - 1) * 8192 + b] : 0;
      }
    }
#pragma unroll
    for (int i = 0; i < 4; ++i) {
      const int bl = wv * 4 + i;
      const int swr = (bl & 7) << 3;
      f16x8 frag[2][2];
#pragma unroll
      for (int rt = 0; rt < 2; ++rt) {
        const int gr = rt * 16 + rc;
        if (gr == 0) {
#pragma unroll
          for (int kh = 0; kh < 2; ++kh)
            frag[rt][kh] = *(const f16x8*)&x3s[bl * 64 + kh * 32 + ko];
        } else if (gr <= 26) {
          const float* src = Wemb + ((size_t)(gr - 1) * 100000 + (size_t)e_idx[i][rt]) * 64;
#pragma unroll
          for (int kh = 0; kh < 2; ++kh) {
            const float* s = src + kh * 32 + ko;
            float4 u = *(const float4*)s;
            float4 v = *(const float4*)(s + 4);
            f16x8 f;
            f[0] = (_Float16)u.x; f[1] = (_Float16)u.y;
            f[2] = (_Float16)u.z; f[3] = (_Float16)u.w;
            f[4] = (_Float16)v.x; f[5] = (_Float16)v.y;
            f[6] = (_Float16)v.z; f[7] = (_Float16)v.w;
            frag[rt][kh] = f;
          }
        } else {
          f16x8 z = {};
          frag[rt][0] = z; frag[rt][1] = z;
        }
      }
      f32x4 z00 = {}, z10 = {}, z11 = {};
#pragma unroll
      for (int kh = 0; kh < 2; ++kh) {
        z00 = __builtin_amdgcn_mfma_f32_16x16x32_f16(frag[0][kh], frag[0][kh], z00, 0, 0, 0);
        z10 = __builtin_amdgcn_mfma_f32_16x16x32_f16(frag[1][kh], frag[0][kh], z10, 0, 0, 0);
        z11 = __builtin_amdgcn_mfma_f32_16x16x32_f16(frag[1][kh], frag[1][kh], z11, 0, 0, 0);
      }
      // x part + K-pad
      Rs[bl * 448 + (lane ^ swr)] = x3s[bl * 64 + lane];
      if (lane < 33) Rs[bl * 448 + ((415 + lane) ^ swr)] = (_Float16)0.0f;
      // Zflat lower triangle
      const int col = lane & 15;
      const int rr0 = (lane >> 4) * 4;
#pragma unroll
      for (int r = 0; r < 4; ++r) {
        const int i0 = rr0 + r;
        if (i0 > col) {
          int p = 64 + i0 * (i0 - 1) / 2 + col;
          Rs[bl * 448 + (p ^ swr)] = (_Float16)z00[r];
        }
        const int i1 = 16 + rr0 + r;
        if (i1 < 27) {
          int p = 64 + i1 * (i1 - 1) / 2 + col;
          Rs[bl * 448 + (p ^ swr)] = (_Float16)z10[r];
          const int j1 = 16 + col;
          if (i1 > j1) {
            int q = 64 + i1 * (i1 - 1) / 2 + j1;
            Rs[bl * 448 + (q ^ swr)] = (_Float16)z11[r];
          }
        }
      }
    }
  }
  __syncthreads();

  // ---- phase 5: t0  z1 = relu(R @ T0^T + tb0), K=448, 64 cols/wave ----
  {
    const int cb = wv * 64;
    f32x4 acc[2][4] = {};
#pragma unroll
    for (int kk = 0; kk < 14; ++kk) {
      f16x8 af[2];
#pragma unroll
      for (int rt = 0; rt < 2; ++rt)
        af[rt] = *(const f16x8*)&Rs[(rt * 16 + rc) * 448 + ((kk * 32 + ko) ^ sw)];
#pragma unroll
      for (int j = 0; j < 4; ++j) {
        f16x8 wf = *(const f16x8*)&t0w[(size_t)(cb + j * 16 + rc) * 448 + kk * 32 + ko];
#pragma unroll
        for (int rt = 0; rt < 2; ++rt)
          acc[rt][j] = __builtin_amdgcn_mfma_f32_16x16x32_f16(af[rt], wf, acc[rt][j], 0, 0, 0);
      }
    }
    // z1 (regA) writes don't clash with Rs (regB) reads; x3 dead.
#pragma unroll
    for (int j = 0; j < 4; ++j) {
      const int col = cb + j * 16 + rc;
      const float bs = tb0[col];
#pragma unroll
      for (int rt = 0; rt < 2; ++rt)
#pragma unroll
        for (int r = 0; r < 4; ++r) {
          int row = rt * 16 + g * 4 + r;
          float v = fmaxf(acc[rt][j][r] + bs, 0.0f);
          z1s[row * 512 + (col ^ ((row & 7) << 3))] = (_Float16)v;
        }
    }
  }
  __syncthreads();

  // ---- phase 6: t1 + final dot/sigmoid, K=512, 32 cols/wave ----
  {
    const int cb = wv * 32;
    f32x4 acc[2][2] = {};
#pragma unroll
    for (int kk = 0; kk < 16; ++kk) {
      f16x8 af[2];
#pragma unroll
      for (int rt = 0; rt < 2; ++rt)
        af[rt] = *(const f16x8*)&z1s[(rt * 16 + rc) * 512 + ((kk * 32 + ko) ^ sw)];
#pragma unroll
      for (int j = 0; j < 2; ++j) {
        f16x8 wf = *(const f16x8*)&t1w[(size_t)(cb + j * 16 + rc) * 512 + kk * 32 + ko];
#pragma unroll
        for (int rt = 0; rt < 2; ++rt)
          acc[rt][j] = __builtin_amdgcn_mfma_f32_16x16x32_f16(af[rt], wf, acc[rt][j], 0, 0, 0);
      }
    }
    float pd[2][4];
#pragma unroll
    for (int rt = 0; rt < 2; ++rt)
#pragma unroll
      for (int r = 0; r < 4; ++r) pd[rt][r] = 0.0f;
#pragma unroll
    for (int j = 0; j < 2; ++j) {
      const int col = cb + j * 16 + rc;
      const float bz = tb1[col];
      const float wz = tW2[col];
#pragma unroll
      for (int rt = 0; rt < 2; ++rt)
#pragma unroll
        for (int r = 0; r < 4; ++r)
          pd[rt][r] += fmaxf(acc[rt][j][r] + bz, 0.0f) * wz;
    }
    __syncthreads();  // Rs reads long done; reuse regB as psum
#pragma unroll
    for (int rt = 0; rt < 2; ++rt)
#pragma unroll
      for (int r = 0; r < 4; ++r) {
        float v = pd[rt][r];
        v += __shfl_xor(v, 1, 64);
        v += __shfl_xor(v, 2, 64);
        v += __shfl_xor(v, 4, 64);
        v += __shfl_xor(v, 8, 64);
        if (rc == 0) psm[wv * 32 + rt * 16 + g * 4 + r] = v;
      }
  }
  __syncthreads();
  if (t < 32) {
    float s = tb2[0];
#pragma unroll
    for (int w = 0; w < 8; ++w) s += psm[w * 32 + t];
    out[b0 + t] = 1.0f / (1.0f + expf(-s));
  }
}

// ---------------------------------------------------------------------------
extern "C" void kernel_launch(void* const* d_in, const int* in_sizes, int n_in,
                              void* d_out, int out_size, void* d_ws, size_t ws_size,
                              hipStream_t stream)
{
  (void)in_sizes; (void)n_in; (void)out_size; (void)ws_size;
  const float* dense = (const float*)d_in[0];
  const int*   lSi   = (const int*)d_in[1];     // lS_o (d_in[2]) unused
  const float* Wemb  = (const float*)d_in[3];
  const float* bW0 = (const float*)d_in[4];  const float* bb0 = (const float*)d_in[5];
  const float* bW1 = (const float*)d_in[6];  const float* bb1 = (const float*)d_in[7];
  const float* bW2 = (const float*)d_in[8];  const float* bb2 = (const float*)d_in[9];
  const float* tW0 = (const float*)d_in[10]; const float* tb0 = (const float*)d_in[11];
  const float* tW1 = (const float*)d_in[12]; const float* tb1 = (const float*)d_in[13];
  const float* tW2 = (const float*)d_in[14]; const float* tb2 = (const float*)d_in[15];
  float* out = (float*)d_out;

  char* ws = (char*)d_ws;
  size_t off = 0;
  auto alloc = [&](size_t bytes) -> void* {
    void* p = ws + off;
    off += (bytes + 255) & ~(size_t)255;
    return p;
  };
  _Float16* w0 = (_Float16*)alloc((size_t)16384 * 2);    // [512][32]
  _Float16* w1 = (_Float16*)alloc((size_t)131072 * 2);   // [256][512]
  _Float16* w2 = (_Float16*)alloc((size_t)16384 * 2);    // [64][256]
  _Float16* t0 = (_Float16*)alloc((size_t)229376 * 2);   // [512][448]
  _Float16* t1 = (_Float16*)alloc((size_t)131072 * 2);   // [256][512]

  prep_kernel<<<2048, 256, 0, stream>>>(bW0, bW1, bW2, tW0, tW1,
                                        w0, w1, w2, t0, t1);
  fused_kernel<<<256, 512, 0, stream>>>(dense, lSi, Wemb,
                                        w0, bb0, w1, bb1, w2, bb2,
                                        t0, tb0, t1, tb1, tW2, tb2, out);
}